// Round 6
// baseline (88.815 us; speedup 1.0000x reference)
//
#include <hip/hip_runtime.h>
#include <math.h>

// CapsShapeLayer: B=256, D=10, M=32, P=36, I=8, O=16, 3 routing iters
// R6: TWO blocks per batch element (grid 512, 5 waves each). Block (b, half)
// duplicates the cheap pre-work (s1->v1->z1 for ALL 10 d, then rinv) so no
// cross-block communication is needed; the expensive tail (y2..out) is split:
// wave w handles d = half*5 + w. LDS 58.5 KB -> 2 blocks/CU co-resident with
// independent barriers (overlap). Half-dot + shfl_xor(1) halves hot LDS reads.
#define BB 256
#define DD 10
#define MM 32
#define PP 36
#define II 8
#define OO 16
#define NT 320        // 5 waves
#define XS 292        // xs per-m stride (= 4*73, odd float4 stride -> banks spread)
#define RS 37         // rinv row stride: gcd(5,32)=1 -> conflict-free

__device__ __forceinline__ float dot8(const float4 a0, const float4 a1,
                                      const float4 b0, const float4 b1) {
    return a0.x*b0.x + a0.y*b0.y + a0.z*b0.z + a0.w*b0.w
         + a1.x*b1.x + a1.y*b1.y + a1.z*b1.z + a1.w*b1.w;
}
__device__ __forceinline__ float dot4(const float4 a, const float4 b) {
    return a.x*b.x + a.y*b.y + a.z*b.z + a.w*b.w;
}

__global__ void __launch_bounds__(NT, 3) caps_routing(
    const float* __restrict__ x,   // (B, M, P, I)
    const float* __restrict__ W,   // (D, M, O, I)
    float* __restrict__ out)       // (B, D, O)
{
    const int bidx = blockIdx.x & 255;      // batch element
    const int half = blockIdx.x >> 8;       // 0 or 1: which 5 d's this block owns
    const int tid  = threadIdx.x;
    const int wave = tid >> 6;              // 0..4
    const int lane = tid & 63;
    const float* __restrict__ xb = x + (size_t)bidx * (MM*PP*II);

    __shared__ __align__(16) float xs  [MM*XS];     // 37376 B  x staged once
    __shared__ __align__(16) float z   [DD*MM*II];  // 10240 B  z1 (all 10 d), then z1+z2 on owned d
    __shared__ __align__(16) float y   [5*MM*II];   //  5120 B  per-wave y scratch
    __shared__ __align__(16) float ybar[MM*II];     //  1024 B
    __shared__ __align__(16) float rinv[MM*RS];     //  4736 B
    // total 58496 B -> 2 blocks/CU

    // ======== stage 0: x -> LDS + ybar (c1 = 1/D exact) ========
    {
        const float4* xg = (const float4*)xb;
        #pragma unroll
        for (int k = 0; k < 8; ++k) {                 // 2304 float4 over 320 thr
            const int t = tid + k*NT;
            if (t < MM*72) {
                const int m = t / 72, r = t - m*72;
                *(float4*)(xs + m*XS + 4*r) = xg[t];
            }
        }
        if (tid < MM*II) {                            // ybar[m,i] = 0.1 * sum_p x
            const int m = tid >> 3, i = tid & 7;
            const float* xr = xb + m*(PP*II) + i;
            float acc = 0.f;
            #pragma unroll 6
            for (int p = 0; p < PP; ++p) acc += xr[p*II];
            ybar[tid] = 0.1f * acc;
        }
    }
    __syncthreads();                                  // BARRIER 1

    // ======== pre-work (duplicated in both halves): s1 -> v1 -> z1 for ALL 10 d ========
    {
        const int o = lane & 15, q = lane >> 4;       // o bits 0-3, m-quarter bits 4-5
        #pragma unroll
        for (int r = 0; r < 2; ++r) {
            const int d = wave + r*5;                 // 5 waves x 2 rounds = 10 d
            float s1 = 0.f;
            #pragma unroll
            for (int j = 0; j < 8; ++j) {
                const int m = q*8 + j;
                const float4* wp = (const float4*)(W + ((size_t)((d*MM + m)*OO + o)) * II);
                const float4* yp = (const float4*)(ybar + m*II);
                s1 += dot8(wp[0], wp[1], yp[0], yp[1]);
            }
            s1 += __shfl_xor(s1, 16, 64);
            s1 += __shfl_xor(s1, 32, 64);
            float sq = s1 * s1;
            sq += __shfl_xor(sq, 1, 64);
            sq += __shfl_xor(sq, 2, 64);
            sq += __shfl_xor(sq, 4, 64);
            sq += __shfl_xor(sq, 8, 64);
            const float v1 = (sq / (1.f + sq)) * (s1 / sqrtf(sq + 1e-7f));
            float vv[OO];
            #pragma unroll
            for (int o2 = 0; o2 < OO; ++o2) vv[o2] = __shfl(v1, o2, 64);
            #pragma unroll
            for (int k = 0; k < 4; ++k) {             // z1[d,m,i] = sum_o W*v1
                const int mi = k*64 + lane;
                const int m = mi >> 3, i = mi & 7;
                const float* wp = W + ((size_t)(d*MM + m)*OO) * II + i;
                float acc = 0.f;
                #pragma unroll
                for (int o2 = 0; o2 < OO; ++o2) acc += wp[o2*II] * vv[o2];
                z[d*(MM*II) + mi] = acc;
            }
        }
    }
    __syncthreads();                                  // BARRIER 2

    // ======== rinv[m,p] = 1 / sum_d exp(x.z1)  (|b| small -> no max needed) ========
    #pragma unroll
    for (int k = 0; k < 4; ++k) {
        const int t = tid + k*NT;
        if (t < MM*PP) {
            const int m = t / PP, p = t - m*PP;       // lanes mostly share m -> z broadcast
            const float4* xp = (const float4*)(xs + m*XS + p*II);
            const float4 x0 = xp[0], x1 = xp[1];
            float se = 0.f;
            #pragma unroll
            for (int d2 = 0; d2 < DD; ++d2) {
                const float4* zp = (const float4*)(z + (d2*MM + m)*II);
                se += __expf(dot8(x0, x1, zp[0], zp[1]));
            }
            rinv[m*RS + p] = 1.0f / se;
        }
    }
    __syncthreads();                                  // BARRIER 3 (last)

    // ======== tail (owned d only): y2 -> s2 -> v2 -> z2 -> final softmax(P) -> s3 -> out ========
    {
        const int d = half*5 + wave;
        float* __restrict__ zd = z + d*(MM*II);
        float* __restrict__ yd = y + wave*(MM*II);

        const int mL = lane >> 1, ih = lane & 1;      // (m, i-half) per lane
        const float* xr = xs + mL*XS + ih*4;          // this lane's 16B half-rows
        const float4 zh = *(const float4*)(zd + mL*II + ih*4);   // z1 half

        // ---- y2: half-dot + shfl_xor(1) combine; one b128 x-read per p ----
        {
            const float* rr = rinv + mL*RS;
            float a0=0.f, a1=0.f, a2=0.f, a3=0.f;
            #pragma unroll 4
            for (int p = 0; p < PP; ++p) {
                const float4 xh = *(const float4*)(xr + p*II);
                float bh = dot4(xh, zh);
                bh += __shfl_xor(bh, 1, 64);          // full b on both half-lanes
                const float e = __expf(bh) * rr[p];
                a0 += e*xh.x; a1 += e*xh.y; a2 += e*xh.z; a3 += e*xh.w;
            }
            *(float4*)(yd + mL*II + ih*4) = make_float4(a0,a1,a2,a3);
        }
        // in-wave LDS write->read ordering via lgkmcnt; no barrier

        // ---- s2 -> v2 ----
        const int o = lane & 15, q = lane >> 4;
        float s2 = 0.f;
        #pragma unroll
        for (int j = 0; j < 8; ++j) {
            const int m = q*8 + j;
            const float4* wp = (const float4*)(W + ((size_t)((d*MM + m)*OO + o)) * II);
            const float4* yp = (const float4*)(yd + m*II);
            s2 += dot8(wp[0], wp[1], yp[0], yp[1]);
        }
        s2 += __shfl_xor(s2, 16, 64);
        s2 += __shfl_xor(s2, 32, 64);
        float sq = s2 * s2;
        sq += __shfl_xor(sq, 1, 64);
        sq += __shfl_xor(sq, 2, 64);
        sq += __shfl_xor(sq, 4, 64);
        sq += __shfl_xor(sq, 8, 64);
        const float v2 = (sq / (1.f + sq)) * (s2 / sqrtf(sq + 1e-7f));
        float vv[OO];
        #pragma unroll
        for (int o2 = 0; o2 < OO; ++o2) vv[o2] = __shfl(v2, o2, 64);

        // ---- z_acc = z1 + z2 (owned slice only) ----
        #pragma unroll
        for (int k = 0; k < 4; ++k) {
            const int mi = k*64 + lane;
            const int m = mi >> 3, i = mi & 7;
            const float* wp = W + ((size_t)(d*MM + m)*OO) * II + i;
            float acc = 0.f;
            #pragma unroll
            for (int o2 = 0; o2 < OO; ++o2) acc += wp[o2*II] * vv[o2];
            zd[mi] += acc;
        }

        // ---- final softmax over P (per (d,m)): single pass, half-dot ----
        {
            const float4 zh2 = *(const float4*)(zd + mL*II + ih*4);   // z1+z2 half
            float se = 0.f;
            float a0=0.f, a1=0.f, a2=0.f, a3=0.f;
            #pragma unroll 4
            for (int p = 0; p < PP; ++p) {
                const float4 xh = *(const float4*)(xr + p*II);
                float bh = dot4(xh, zh2);
                bh += __shfl_xor(bh, 1, 64);
                const float e = __expf(bh);
                se += e;
                a0 += e*xh.x; a1 += e*xh.y; a2 += e*xh.z; a3 += e*xh.w;
            }
            const float rs = 1.f / se;
            *(float4*)(yd + mL*II + ih*4) = make_float4(a0*rs, a1*rs, a2*rs, a3*rs);
        }

        // ---- s3 -> squash -> out ----
        float s3 = 0.f;
        #pragma unroll
        for (int j = 0; j < 8; ++j) {
            const int m = q*8 + j;
            const float4* wp = (const float4*)(W + ((size_t)((d*MM + m)*OO + o)) * II);
            const float4* yp = (const float4*)(yd + m*II);
            s3 += dot8(wp[0], wp[1], yp[0], yp[1]);
        }
        s3 += __shfl_xor(s3, 16, 64);
        s3 += __shfl_xor(s3, 32, 64);
        float sq3 = s3 * s3;
        sq3 += __shfl_xor(sq3, 1, 64);
        sq3 += __shfl_xor(sq3, 2, 64);
        sq3 += __shfl_xor(sq3, 4, 64);
        sq3 += __shfl_xor(sq3, 8, 64);
        const float r = (sq3 / (1.f + sq3)) * (s3 / sqrtf(sq3 + 1e-7f));
        if (lane < OO)
            out[(size_t)bidx * (DD*OO) + d*OO + o] = r;
    }
}

extern "C" void kernel_launch(void* const* d_in, const int* in_sizes, int n_in,
                              void* d_out, int out_size, void* d_ws, size_t ws_size,
                              hipStream_t stream) {
    (void)in_sizes; (void)n_in; (void)out_size; (void)d_ws; (void)ws_size;
    const float* x = (const float*)d_in[0];  // (B, M, P, I)
    const float* W = (const float*)d_in[1];  // (1, D, M, 1, O, I)
    float* out = (float*)d_out;              // (B, D, O)
    caps_routing<<<dim3(BB*2), dim3(NT), 0, stream>>>(x, W, out);
}

// Round 7
// 78.050 us; speedup vs baseline: 1.1379x; 1.1379x over previous
//
#include <hip/hip_runtime.h>
#include <math.h>

// CapsShapeLayer: B=256, D=10, M=32, P=36, I=8, O=16, 3 routing iters
// R7: R5 skeleton (1 block/batch, 10 waves, wave owns d, 3 barriers) with
// W-access fixes: z-stages load W as contiguous b128 over o (not strided
// dwords); z2 stays entirely in registers (no LDS pass); rinv p-minor map.
#define BB 256
#define DD 10
#define MM 32
#define PP 36
#define II 8
#define OO 16
#define NT 640        // 10 waves = one per d
#define XS 292        // xs per-m stride (= 4*73, odd-chunk stride -> even bank-quad spread)
#define RS 37         // rinv row stride: gcd(5,32)=1 -> conflict-free over m

__device__ __forceinline__ float dot8(const float4 a0, const float4 a1,
                                      const float4 b0, const float4 b1) {
    return a0.x*b0.x + a0.y*b0.y + a0.z*b0.z + a0.w*b0.w
         + a1.x*b1.x + a1.y*b1.y + a1.z*b1.z + a1.w*b1.w;
}
__device__ __forceinline__ float dot4(const float4 a, const float4 b) {
    return a.x*b.x + a.y*b.y + a.z*b.z + a.w*b.w;
}

__global__ void __launch_bounds__(NT, 3) caps_routing(
    const float* __restrict__ x,   // (B, M, P, I)
    const float* __restrict__ W,   // (D, M, O, I)
    float* __restrict__ out)       // (B, D, O)
{
    const int bidx = blockIdx.x;
    const int tid  = threadIdx.x;
    const int wave = tid >> 6;          // d owned by this wave (0..9)
    const int lane = tid & 63;
    const float* __restrict__ xb = x + (size_t)bidx * (MM*PP*II);

    __shared__ __align__(16) float xs  [MM*XS];     // 37376 B  x staged once
    __shared__ __align__(16) float z   [DD*MM*II];  // 10240 B  z1 (rinv needs all d)
    __shared__ __align__(16) float y   [DD*MM*II];  // 10240 B  per-wave y scratch
    __shared__ __align__(16) float ybar[MM*II];     //  1024 B
    __shared__ __align__(16) float rinv[MM*RS];     //  4736 B
    // total 63616 B

    // ======== stage 0: x -> LDS + ybar (c1 = 1/D exact) ========
    {
        const float4* xg = (const float4*)xb;
        #pragma unroll
        for (int k = 0; k < 4; ++k) {                 // 2304 float4 over 640 thr
            const int t = tid + k*NT;
            if (t < MM*72) {
                const int m = t / 72, r = t - m*72;
                *(float4*)(xs + m*XS + 4*r) = xg[t];
            }
        }
        if (tid < MM*II) {                            // ybar[m,i] = 0.1 * sum_p x
            const int m = tid >> 3, i = tid & 7;
            const float* xr = xb + m*(PP*II) + i;
            float acc = 0.f;
            #pragma unroll 6
            for (int p = 0; p < PP; ++p) acc += xr[p*II];
            ybar[tid] = 0.1f * acc;
        }
    }
    __syncthreads();                                  // BARRIER 1

    // ======== per-wave (d = wave): s1 -> v1 -> z1 ========
    {
        const int d = wave;
        const int o = lane & 15, q = lane >> 4;       // o bits 0-3, m-quarter bits 4-5
        float s1 = 0.f;
        #pragma unroll
        for (int j = 0; j < 8; ++j) {
            const int m = q*8 + j;
            const float4* wp = (const float4*)(W + ((size_t)((d*MM + m)*OO + o)) * II);
            const float4* yp = (const float4*)(ybar + m*II);
            s1 += dot8(wp[0], wp[1], yp[0], yp[1]);
        }
        s1 += __shfl_xor(s1, 16, 64);                 // reduce over m-quarters
        s1 += __shfl_xor(s1, 32, 64);
        float sq = s1 * s1;                           // squash: sum s^2 over o
        sq += __shfl_xor(sq, 1, 64);
        sq += __shfl_xor(sq, 2, 64);
        sq += __shfl_xor(sq, 4, 64);
        sq += __shfl_xor(sq, 8, 64);
        const float v1 = (sq / (1.f + sq)) * (s1 / sqrtf(sq + 1e-7f));
        float vv[OO];
        #pragma unroll
        for (int o2 = 0; o2 < OO; ++o2) vv[o2] = __shfl(v1, o2, 64);

        // z1: lane = (m, i-half); W loaded as b128 over o (contiguous 16B, stride 32B)
        const int mz = lane >> 1, ihz = lane & 1;
        const float* wz = W + ((size_t)(d*MM + mz)*OO) * II + ihz*4;
        float a0 = 0.f, a1 = 0.f, a2 = 0.f, a3 = 0.f;
        #pragma unroll
        for (int o2 = 0; o2 < OO; ++o2) {
            const float4 wv = *(const float4*)(wz + o2*II);
            a0 += wv.x * vv[o2]; a1 += wv.y * vv[o2];
            a2 += wv.z * vv[o2]; a3 += wv.w * vv[o2];
        }
        *(float4*)(z + (d*MM + mz)*II + ihz*4) = make_float4(a0, a1, a2, a3);
    }
    __syncthreads();                                  // BARRIER 2

    // ======== rinv[m,p] = 1 / sum_d exp(x.z1)  (p-minor: z reads broadcast) ========
    #pragma unroll
    for (int k = 0; k < 2; ++k) {
        const int t = tid + k*NT;
        if (t < MM*PP) {
            const int m = t / PP, p = t - m*PP;
            const float4* xp = (const float4*)(xs + m*XS + p*II);
            const float4 x0 = xp[0], x1 = xp[1];
            float se = 0.f;
            #pragma unroll
            for (int d2 = 0; d2 < DD; ++d2) {
                const float4* zp = (const float4*)(z + (d2*MM + m)*II);
                se += __expf(dot8(x0, x1, zp[0], zp[1]));
            }
            rinv[m*RS + p] = 1.0f / se;
        }
    }
    __syncthreads();                                  // BARRIER 3 (last)

    // ======== tail (d = wave): y2 -> s2 -> v2 -> z2(regs) -> final -> s3 -> out ========
    {
        const int d = wave;
        const float* __restrict__ zd = z + d*(MM*II);
        float* __restrict__ yd = y + d*(MM*II);

        const int mL = lane >> 1, ih = lane & 1;      // (m, i-half) per lane
        const float* xr = xs + mL*XS + ih*4;          // this lane's 16B half-rows
        const float4 zh = *(const float4*)(zd + mL*II + ih*4);   // z1 half

        // ---- y2: half-dot + shfl_xor(1); one b128 x-read per p ----
        {
            const float* rr = rinv + mL*RS;
            float a0=0.f, a1=0.f, a2=0.f, a3=0.f;
            #pragma unroll 6
            for (int p = 0; p < PP; ++p) {
                const float4 xh = *(const float4*)(xr + p*II);
                float bh = dot4(xh, zh);
                bh += __shfl_xor(bh, 1, 64);          // full b on both half-lanes
                const float e = __expf(bh) * rr[p];
                a0 += e*xh.x; a1 += e*xh.y; a2 += e*xh.z; a3 += e*xh.w;
            }
            *(float4*)(yd + mL*II + ih*4) = make_float4(a0,a1,a2,a3);
        }
        // in-wave LDS write->read ordering via lgkmcnt; no barrier

        // ---- s2 -> v2 ----
        const int o = lane & 15, q = lane >> 4;
        float s2 = 0.f;
        #pragma unroll
        for (int j = 0; j < 8; ++j) {
            const int m = q*8 + j;
            const float4* wp = (const float4*)(W + ((size_t)((d*MM + m)*OO + o)) * II);
            const float4* yp = (const float4*)(yd + m*II);
            s2 += dot8(wp[0], wp[1], yp[0], yp[1]);
        }
        s2 += __shfl_xor(s2, 16, 64);
        s2 += __shfl_xor(s2, 32, 64);
        float sq = s2 * s2;
        sq += __shfl_xor(sq, 1, 64);
        sq += __shfl_xor(sq, 2, 64);
        sq += __shfl_xor(sq, 4, 64);
        sq += __shfl_xor(sq, 8, 64);
        const float v2 = (sq / (1.f + sq)) * (s2 / sqrtf(sq + 1e-7f));
        float vv[OO];
        #pragma unroll
        for (int o2 = 0; o2 < OO; ++o2) vv[o2] = __shfl(v2, o2, 64);

        // ---- z2 in registers only: this lane's (mL, ih) slice; b128 W loads over o ----
        float4 zh2;
        {
            const float* wz = W + ((size_t)(d*MM + mL)*OO) * II + ih*4;
            float a0 = 0.f, a1 = 0.f, a2 = 0.f, a3 = 0.f;
            #pragma unroll
            for (int o2 = 0; o2 < OO; ++o2) {
                const float4 wv = *(const float4*)(wz + o2*II);
                a0 += wv.x * vv[o2]; a1 += wv.y * vv[o2];
                a2 += wv.z * vv[o2]; a3 += wv.w * vv[o2];
            }
            zh2 = make_float4(zh.x + a0, zh.y + a1, zh.z + a2, zh.w + a3);
        }

        // ---- final softmax over P (per (d,m)): single pass, half-dot ----
        {
            float se = 0.f;
            float a0=0.f, a1=0.f, a2=0.f, a3=0.f;
            #pragma unroll 6
            for (int p = 0; p < PP; ++p) {
                const float4 xh = *(const float4*)(xr + p*II);
                float bh = dot4(xh, zh2);
                bh += __shfl_xor(bh, 1, 64);
                const float e = __expf(bh);
                se += e;
                a0 += e*xh.x; a1 += e*xh.y; a2 += e*xh.z; a3 += e*xh.w;
            }
            const float rs = 1.f / se;
            *(float4*)(yd + mL*II + ih*4) = make_float4(a0*rs, a1*rs, a2*rs, a3*rs);
        }

        // ---- s3 -> squash -> out ----
        float s3 = 0.f;
        #pragma unroll
        for (int j = 0; j < 8; ++j) {
            const int m = q*8 + j;
            const float4* wp = (const float4*)(W + ((size_t)((d*MM + m)*OO + o)) * II);
            const float4* yp = (const float4*)(yd + m*II);
            s3 += dot8(wp[0], wp[1], yp[0], yp[1]);
        }
        s3 += __shfl_xor(s3, 16, 64);
        s3 += __shfl_xor(s3, 32, 64);
        float sq3 = s3 * s3;
        sq3 += __shfl_xor(sq3, 1, 64);
        sq3 += __shfl_xor(sq3, 2, 64);
        sq3 += __shfl_xor(sq3, 4, 64);
        sq3 += __shfl_xor(sq3, 8, 64);
        const float r = (sq3 / (1.f + sq3)) * (s3 / sqrtf(sq3 + 1e-7f));
        if (lane < OO)
            out[(size_t)bidx * (DD*OO) + d*OO + o] = r;
    }
}

extern "C" void kernel_launch(void* const* d_in, const int* in_sizes, int n_in,
                              void* d_out, int out_size, void* d_ws, size_t ws_size,
                              hipStream_t stream) {
    (void)in_sizes; (void)n_in; (void)out_size; (void)d_ws; (void)ws_size;
    const float* x = (const float*)d_in[0];  // (B, M, P, I)
    const float* W = (const float*)d_in[1];  // (1, D, M, 1, O, I)
    float* out = (float*)d_out;              // (B, D, O)
    caps_routing<<<dim3(BB), dim3(NT), 0, stream>>>(x, W, out);
}